// Round 15
// baseline (1088.356 us; speedup 1.0000x reference)
//
#include <hip/hip_runtime.h>
#include <math.h>

#define BB 32
#define SS 65536
#define CC 20
#define NM 16
#define HH 128
#define RP 264   // DFT LDS row pitch (bf16 elems)
#define WP 72    // hT row pitch (bf16 elems): 36 dwords; b128-aligned rows
#define NSLOT 16

using short8  = __attribute__((ext_vector_type(8))) short;
using floatx4 = __attribute__((ext_vector_type(4))) float;
using float2v = __attribute__((ext_vector_type(2))) float;

__device__ __forceinline__ unsigned short f2bf(float f) {
    union { float f; unsigned u; } v; v.f = f;
    unsigned u = v.u;
    return (unsigned short)((u + 0x7FFFu + ((u >> 16) & 1u)) >> 16);   // RNE
}
__device__ __forceinline__ float bf2f(unsigned short h) {
    union { unsigned u; float f; } v; v.u = ((unsigned)h) << 16; return v.f;
}
__device__ __forceinline__ unsigned short f2bflo(float a) {
    return f2bf(a - bf2f(f2bf(a)));
}

// Tanh-form gelu (R11). Packed pair version: 3 packed VALU + 4 trans.
__device__ __forceinline__ float gelu_fast(float v) {
    float u = v * v;
    float inner = v * fmaf(0.0356774081f, u, 0.7978845608f);
    float e = __builtin_amdgcn_exp2f(inner * 2.8853900818f);
    float r = __builtin_amdgcn_rcpf(e + 1.0f);
    return fmaf(-v, r, v);
}
__device__ __forceinline__ float2v gelu2(float2v v) {
    float2v u = v * v;
    float2v inner = v * (u * 0.0356774081f + 0.7978845608f);
    float e0 = __builtin_amdgcn_exp2f(inner.x * 2.8853900818f);
    float e1 = __builtin_amdgcn_exp2f(inner.y * 2.8853900818f);
    float2v r = { __builtin_amdgcn_rcpf(e0 + 1.0f), __builtin_amdgcn_rcpf(e1 + 1.0f) };
    return v - v * r;
}

// ---------------- k_prep: max-reduce + zero cP + w1T + wwT(4 layers) --------
// wwT[l][c][o] = ww_l[o][c] — o-pairs adjacent for packed-fp32 point-op.
__global__ __launch_bounds__(256) void k_prep(const float* __restrict__ pd,
                                              const float* __restrict__ w1,
                                              const float* __restrict__ ww0,
                                              const float* __restrict__ ww1,
                                              const float* __restrict__ ww2,
                                              const float* __restrict__ ww3,
                                              float* __restrict__ invmax,
                                              float* __restrict__ cP,
                                              unsigned short* __restrict__ w1Tg,
                                              float* __restrict__ wwT) {
    int bx = blockIdx.x;
    if (bx == 0) {
        __shared__ float red[256];
        int t = threadIdx.x;
        float m = -1e30f;
        for (int i = t; i < SS; i += 256) m = fmaxf(m, pd[i]);
        red[t] = m; __syncthreads();
        for (int off = 128; off > 0; off >>= 1) {
            if (t < off) red[t] = fmaxf(red[t], red[t + off]);
            __syncthreads();
        }
        if (t == 0) invmax[0] = 1.0f / red[0];
    } else if (bx <= 1280) {
        int idx = (bx - 1) * 256 + threadIdx.x;   // 1280*256 float4 = 4*16*32*640 floats
        float4 z = {0.f, 0.f, 0.f, 0.f};
        ((float4*)cP)[idx] = z;
    } else {
        for (int idx = threadIdx.x; idx < HH * 64; idx += 256) {
            int j = idx >> 6, k = idx & 63;
            unsigned short r = 0;
            if (k < CC) r = f2bf(w1[k * HH + j]);
            else if (k >= 32 && k < 32 + CC) r = f2bflo(w1[(k - 32) * HH + j]);
            w1Tg[idx] = r;
        }
        const float* wws[4] = {ww0, ww1, ww2, ww3};
        for (int idx = threadIdx.x; idx < 4 * CC * CC; idx += 256) {
            int l = idx / (CC * CC), rem = idx - l * CC * CC;
            int c = rem / CC, o = rem - c * CC;
            wwT[idx] = wws[l][o * CC + c];
        }
    }
}

// ---------------- shared DFT tail: LDS-staged MFMA partial DFT --------------
__device__ __forceinline__ void dft_phase(unsigned short* sh_hA, unsigned short* sh_ph,
                                          int tid, float* cPdst) {
    int wave = tid >> 6, lane = tid & 63;
    int quad = lane >> 4, frow = lane & 15;
    floatx4 acc00 = {0.f,0.f,0.f,0.f}, acc01 = {0.f,0.f,0.f,0.f};
    floatx4 acc10 = {0.f,0.f,0.f,0.f}, acc11 = {0.f,0.f,0.f,0.f};
    int kb = wave * 64 + quad * 8;
    #pragma unroll
    for (int kc = 0; kc < 2; ++kc) {
        int k = kb + kc * 32;
        short8 a0 = *(const short8*)(sh_hA + frow * RP + k);
        short8 a1 = *(const short8*)(sh_hA + (16 + frow) * RP + k);
        short8 bc = *(const short8*)(sh_ph + frow * RP + k);
        short8 bs = *(const short8*)(sh_ph + (16 + frow) * RP + k);
        acc00 = __builtin_amdgcn_mfma_f32_16x16x32_bf16(a0, bc, acc00, 0, 0, 0);
        acc01 = __builtin_amdgcn_mfma_f32_16x16x32_bf16(a0, bs, acc01, 0, 0, 0);
        acc10 = __builtin_amdgcn_mfma_f32_16x16x32_bf16(a1, bc, acc10, 0, 0, 0);
        acc11 = __builtin_amdgcn_mfma_f32_16x16x32_bf16(a1, bs, acc11, 0, 0, 0);
    }
    __syncthreads();
    float* red = (float*)sh_hA;
    #pragma unroll
    for (int r = 0; r < 4; ++r) {
        red[wave * 1024 + 0 * 256 + r * 64 + lane] = acc00[r];
        red[wave * 1024 + 1 * 256 + r * 64 + lane] = acc01[r];
        red[wave * 1024 + 2 * 256 + r * 64 + lane] = acc10[r];
        red[wave * 1024 + 3 * 256 + r * 64 + lane] = acc11[r];
    }
    __syncthreads();
    #pragma unroll
    for (int ii = 0; ii < 4; ++ii) {
        int idx = ii * 256 + tid;
        float v = red[idx] + red[1024 + idx] + red[2048 + idx] + red[3072 + idx];
        int f = idx >> 8;
        int r = (idx >> 6) & 3, ln = idx & 63;
        int o = (f >> 1) * 16 + (ln >> 4) * 4 + r;   // D row = quad*4+reg
        int m = ln & 15;                              // D col = lane&15
        if (o < CC) atomicAdd(cPdst + (f & 1) * 320 + o * 16 + m, v);
    }
}

// ---------------- k_fc0_dft: h2 (paired bf16 dwords) = fc0; DFT partials ----
__global__ __launch_bounds__(256, 4) void k_fc0_dft(const float* __restrict__ x,
        const float* __restrict__ pd, const float* __restrict__ w,
        const float* __restrict__ bias, const float* __restrict__ invmax,
        unsigned* __restrict__ h2, float* __restrict__ cP0) {
    __shared__ __align__(16) unsigned short sh_hA[32 * RP];
    __shared__ __align__(16) unsigned short sh_ph[32 * RP];
    int tid = threadIdx.x;
    {
        unsigned* z = (unsigned*)(sh_hA + CC * RP);
        for (int i = tid; i < (32 - CC) * RP / 2; i += 256) z[i] = 0;
    }
    int b = blockIdx.y;
    int s = blockIdx.x * 256 + tid;
    float xv = x[(size_t)b * SS + s];
    float g  = pd[s] * invmax[0];
    unsigned* hp2 = h2 + (size_t)b * (CC / 2) * SS + s;
    float u = (float)s * (1.0f / 32768.0f);
    float s1, c1; sincospif(u, &s1, &c1);
    float cm = 1.0f, sm = 0.0f;
    #pragma unroll
    for (int m = 0; m < NM; ++m) {
        sh_ph[m * RP + tid]        = f2bf(cm);
        sh_ph[(16 + m) * RP + tid] = f2bf(sm);
        float cn = cm * c1 - sm * s1;
        sm = sm * c1 + cm * s1;
        cm = cn;
    }
    #pragma unroll
    for (int p = 0; p < CC / 2; ++p) {
        int c0 = 2 * p, c1i = 2 * p + 1;
        float v0 = xv * w[c0]  + g * w[CC + c0]  + bias[c0];
        float v1 = xv * w[c1i] + g * w[CC + c1i] + bias[c1i];
        unsigned short a0 = f2bf(v0), a1 = f2bf(v1);
        hp2[(size_t)p * SS] = (unsigned)a0 | ((unsigned)a1 << 16);
        sh_hA[c0 * RP + tid]  = a0;
        sh_hA[c1i * RP + tid] = a1;
    }
    __syncthreads();
    dft_phase(sh_hA, sh_ph, tid, cP0 + ((size_t)(blockIdx.x & (NSLOT - 1)) * BB + b) * 640);
}

// ---------------- k_point_dft (layers 0..2): packed-fp32 point-op + DFT -----
// wwT: [c][o] (o-pairs adjacent); cAt/cBt: [m][o] (o-pairs adjacent).
__global__ __launch_bounds__(256, 4) void k_point_dft(unsigned* __restrict__ h2,
        const float* __restrict__ wwT, const float* __restrict__ wb,
        const float* __restrict__ cAt, const float* __restrict__ cBt,
        float* __restrict__ cPn) {
    __shared__ __align__(16) unsigned short sh_hA[32 * RP];
    __shared__ __align__(16) unsigned short sh_ph[32 * RP];
    int tid = threadIdx.x;
    int b = blockIdx.y;
    {
        unsigned* z = (unsigned*)(sh_hA + CC * RP);
        for (int i = tid; i < (32 - CC) * RP / 2; i += 256) z[i] = 0;
    }
    const float* wA = cAt + (size_t)b * NM * CC;
    const float* wB = cBt + (size_t)b * NM * CC;
    int s = blockIdx.x * 256 + tid;
    unsigned* hp2 = h2 + (size_t)b * (CC / 2) * SS + s;
    float u = (float)s * (1.0f / 32768.0f);
    float s1, c1; sincospif(u, &s1, &c1);
    float cm[NM], sm[NM];
    cm[0] = 1.0f; sm[0] = 0.0f;
    #pragma unroll
    for (int m = 1; m < NM; ++m) {
        cm[m] = cm[m - 1] * c1 - sm[m - 1] * s1;
        sm[m] = sm[m - 1] * c1 + cm[m - 1] * s1;
    }
    #pragma unroll
    for (int m = 0; m < NM; ++m) {
        sh_ph[m * RP + tid]        = f2bf(cm[m]);
        sh_ph[(16 + m) * RP + tid] = f2bf(sm[m]);
    }
    float hv[CC];
    #pragma unroll
    for (int p = 0; p < CC / 2; ++p) {
        unsigned hw = hp2[(size_t)p * SS];
        hv[2 * p]     = bf2f((unsigned short)(hw & 0xFFFFu));
        hv[2 * p + 1] = bf2f((unsigned short)(hw >> 16));
    }
    #pragma unroll 2
    for (int p = 0; p < CC / 2; ++p) {
        float2v acc = *(const float2v*)(wb + 2 * p);
        #pragma unroll
        for (int c = 0; c < CC; ++c)
            acc += (*(const float2v*)(wwT + c * CC + 2 * p)) * hv[c];
        #pragma unroll
        for (int m = 0; m < NM; ++m)
            acc += (*(const float2v*)(wA + m * CC + 2 * p)) * cm[m]
                 + (*(const float2v*)(wB + m * CC + 2 * p)) * sm[m];
        acc = gelu2(acc);
        unsigned short b0 = f2bf(acc.x), b1 = f2bf(acc.y);
        hp2[(size_t)p * SS] = (unsigned)b0 | ((unsigned)b1 << 16);
        sh_hA[(2 * p) * RP + tid]     = b0;
        sh_hA[(2 * p + 1) * RP + tid] = b1;
    }
    __syncthreads();
    dft_phase(sh_hA, sh_ph, tid, cPn + ((size_t)(blockIdx.x & (NSLOT - 1)) * BB + b) * 640);
}

// ---------------- k_mix: 16-slot reduce + mixing -> TRANSPOSED cAt/cBt ------
__global__ __launch_bounds__(320) void k_mix(const float* __restrict__ cP,
                                             const float* __restrict__ wre, const float* __restrict__ wim,
                                             float* __restrict__ cAt, float* __restrict__ cBt) {
    int b = blockIdx.x, tid = threadIdx.x;
    __shared__ float PQ[640];
    const float* base = cP + (size_t)b * 640;
    int i = tid >> 4, m = tid & 15;
    float sP = 0.f, sQ = 0.f;
    #pragma unroll 4
    for (int sl = 0; sl < NSLOT; ++sl) {
        sP += base[(size_t)sl * BB * 640 + tid];
        sQ += base[(size_t)sl * BB * 640 + 320 + tid];
    }
    PQ[i * 32 + m]      = sP;
    PQ[i * 32 + 16 + m] = sQ;
    __syncthreads();
    int o = i;
    float reY = 0.f, imY = 0.f;
    #pragma unroll
    for (int c = 0; c < CC; ++c) {
        float P = PQ[c * 32 + m], Q = PQ[c * 32 + 16 + m];
        float wr = wre[(size_t)(c * CC + o) * NM + m];
        float wi = wim[(size_t)(c * CC + o) * NM + m];
        reY += P * wr + Q * wi;                // X = P - iQ
        imY += P * wi - Q * wr;
    }
    const float invS = 1.0f / (float)SS;
    float a, bb;
    if (m == 0) { a = reY * invS; bb = 0.0f; } // irfft drops Im(DC)
    else        { a = 2.0f * reY * invS; bb = -2.0f * imY * invS; }
    cAt[((size_t)b * NM + m) * CC + o] = a;    // [m][o] — o-pairs adjacent
    cBt[((size_t)b * NM + m) * CC + o] = bb;
}

// ---------------- k_point_final: packed point-op + fc1 MFMA + gelu2 + fc2 ---
__global__ __launch_bounds__(256, 2) void k_point_final(const unsigned* __restrict__ h2,
        const float* __restrict__ wwT, const float* __restrict__ wb,
        const float* __restrict__ cAt, const float* __restrict__ cBt,
        const unsigned short* __restrict__ w1Tg, const float* __restrict__ b1,
        const float* __restrict__ w2, const float* __restrict__ b2,
        float* __restrict__ out) {
    __shared__ __align__(16) unsigned short hT[256 * WP];   // 36.9 KB
    __shared__ float outS[256];
    int tid = threadIdx.x;
    int b = blockIdx.y;
    const float* wA = cAt + (size_t)b * NM * CC;
    const float* wB = cBt + (size_t)b * NM * CC;

    // point op (layer 3, no gelu), pack own hT row
    int s = blockIdx.x * 256 + tid;
    const unsigned* hp2 = h2 + (size_t)b * (CC / 2) * SS + s;
    float u = (float)s * (1.0f / 32768.0f);
    float s1, c1; sincospif(u, &s1, &c1);
    float cm[NM], sm[NM];
    cm[0] = 1.0f; sm[0] = 0.0f;
    #pragma unroll
    for (int m = 1; m < NM; ++m) {
        cm[m] = cm[m - 1] * c1 - sm[m - 1] * s1;
        sm[m] = sm[m - 1] * c1 + cm[m - 1] * s1;
    }
    float hv[CC];
    #pragma unroll
    for (int p = 0; p < CC / 2; ++p) {
        unsigned hw = hp2[(size_t)p * SS];
        hv[2 * p]     = bf2f((unsigned short)(hw & 0xFFFFu));
        hv[2 * p + 1] = bf2f((unsigned short)(hw >> 16));
    }
    short8 rowf[8];
    #pragma unroll
    for (int ch = 0; ch < 8; ++ch) rowf[ch] = (short8){0,0,0,0,0,0,0,0};
    #pragma unroll        // FULL unroll required (R5 scratch lesson)
    for (int p = 0; p < CC / 2; ++p) {
        float2v acc = *(const float2v*)(wb + 2 * p);
        #pragma unroll
        for (int c = 0; c < CC; ++c)
            acc += (*(const float2v*)(wwT + c * CC + 2 * p)) * hv[c];
        #pragma unroll
        for (int m = 0; m < NM; ++m)
            acc += (*(const float2v*)(wA + m * CC + 2 * p)) * cm[m]
                 + (*(const float2v*)(wB + m * CC + 2 * p)) * sm[m];
        int o0 = 2 * p, o1 = 2 * p + 1;
        unsigned short h0 = f2bf(acc.x), h1 = f2bf(acc.y);
        rowf[o0 >> 3][o0 & 7]       = (short)h0;
        rowf[4 + (o0 >> 3)][o0 & 7] = (short)f2bf(acc.x - bf2f(h0));
        rowf[o1 >> 3][o1 & 7]       = (short)h1;
        rowf[4 + (o1 >> 3)][o1 & 7] = (short)f2bf(acc.y - bf2f(h1));
    }
    #pragma unroll
    for (int ch = 0; ch < 8; ++ch)
        *(short8*)(hT + tid * WP + ch * 8) = rowf[ch];
    __syncthreads();

    // fc1 B-fragments from global (L2-resident) — after the point-op (R8)
    int wave = tid >> 6, lane = tid & 63;
    int col = lane & 15, quad = lane >> 4;
    short8 bhi[8], blo[8];
    #pragma unroll
    for (int nt = 0; nt < 8; ++nt) {
        bhi[nt] = *(const short8*)(w1Tg + (size_t)(nt * 16 + col) * 64 + quad * 8);
        blo[nt] = *(const short8*)(w1Tg + (size_t)(nt * 16 + col) * 64 + 32 + quad * 8);
    }
    float lb1r[8], w2r[8];
    #pragma unroll
    for (int nt = 0; nt < 8; ++nt) { lb1r[nt] = b1[nt * 16 + col]; w2r[nt] = w2[nt * 16 + col]; }
    float b2v = b2[0];
    #pragma unroll
    for (int mt = 0; mt < 4; ++mt) {
        int srow = wave * 64 + mt * 16 + col;     // A row m = lane&15
        short8 ahi = *(const short8*)(hT + srow * WP + quad * 8);
        short8 alo = *(const short8*)(hT + srow * WP + 32 + quad * 8);
        float2v part01 = {0.f, 0.f}, part23 = {0.f, 0.f};
        #pragma unroll
        for (int nt = 0; nt < 8; ++nt) {
            floatx4 a = {0.f, 0.f, 0.f, 0.f};
            a = __builtin_amdgcn_mfma_f32_16x16x32_bf16(ahi, bhi[nt], a, 0, 0, 0);
            a = __builtin_amdgcn_mfma_f32_16x16x32_bf16(ahi, blo[nt], a, 0, 0, 0);
            a = __builtin_amdgcn_mfma_f32_16x16x32_bf16(alo, bhi[nt], a, 0, 0, 0);
            float2v t01 = gelu2((float2v){a[0] + lb1r[nt], a[1] + lb1r[nt]});
            float2v t23 = gelu2((float2v){a[2] + lb1r[nt], a[3] + lb1r[nt]});
            part01 += t01 * w2r[nt];
            part23 += t23 * w2r[nt];
        }
        float part[4] = {part01.x, part01.y, part23.x, part23.y};
        #pragma unroll
        for (int r = 0; r < 4; ++r) {
            float p = part[r];
            p += __shfl_xor(p, 1, 64);
            p += __shfl_xor(p, 2, 64);
            p += __shfl_xor(p, 4, 64);
            p += __shfl_xor(p, 8, 64);
            if (col == 0) outS[wave * 64 + mt * 16 + quad * 4 + r] = p + b2v;
        }
    }
    __syncthreads();
    out[(size_t)b * SS + blockIdx.x * 256 + tid] = outS[tid];
}

extern "C" void kernel_launch(void* const* d_in, const int* in_sizes, int n_in,
                              void* d_out, int out_size, void* d_ws, size_t ws_size,
                              hipStream_t stream) {
    (void)in_sizes; (void)n_in; (void)out_size; (void)ws_size;
    const float* x    = (const float*)d_in[0];
    const float* pd   = (const float*)d_in[1];
    const float* fc0w = (const float*)d_in[2];
    const float* fc0b = (const float*)d_in[3];
    const float* fc1w = (const float*)d_in[4];
    const float* fc1b = (const float*)d_in[5];
    const float* fc2w = (const float*)d_in[6];
    const float* fc2b = (const float*)d_in[7];

    char* ws = (char*)d_ws;
    unsigned* h2 = (unsigned*)ws;
    size_t off = (size_t)BB * (CC / 2) * SS * 4;                      // 83.9 MB (paired bf16)
    float* cP = (float*)(ws + off); off += (size_t)4 * NSLOT * BB * 640 * 4;  // 5.24 MB
    float* cAt = (float*)(ws + off); off += (size_t)BB * NM * CC * 4;
    float* cBt = (float*)(ws + off); off += (size_t)BB * NM * CC * 4;
    float* invmax = (float*)(ws + off); off += 256;
    unsigned short* w1Tg = (unsigned short*)(ws + off); off += (size_t)HH * 64 * 2;  // 16 KB
    float* wwT = (float*)(ws + off); off += (size_t)4 * CC * CC * 4;  // 6.4 KB
    const size_t CPL = (size_t)NSLOT * BB * 640;   // floats per layer-slot set

    dim3 gBS(SS / 256, BB);

    k_prep<<<1282, 256, 0, stream>>>(pd, fc1w,
                                     (const float*)d_in[10], (const float*)d_in[14],
                                     (const float*)d_in[18], (const float*)d_in[22],
                                     invmax, cP, w1Tg, wwT);
    k_fc0_dft<<<gBS, 256, 0, stream>>>(x, pd, fc0w, fc0b, invmax, h2, cP);

    for (int l = 0; l < 3; ++l) {
        const float* wre = (const float*)d_in[8 + 4 * l];
        const float* wim = (const float*)d_in[9 + 4 * l];
        const float* wb  = (const float*)d_in[11 + 4 * l];
        k_mix<<<BB, 320, 0, stream>>>(cP + (size_t)l * CPL, wre, wim, cAt, cBt);
        k_point_dft<<<gBS, 256, 0, stream>>>(h2, wwT + (size_t)l * CC * CC, wb, cAt, cBt,
                                             cP + (size_t)(l + 1) * CPL);
    }
    {   // layer 3 fused with fc1/gelu/fc2
        const float* wre = (const float*)d_in[20];
        const float* wim = (const float*)d_in[21];
        const float* wb  = (const float*)d_in[23];
        k_mix<<<BB, 320, 0, stream>>>(cP + (size_t)3 * CPL, wre, wim, cAt, cBt);
        k_point_final<<<gBS, 256, 0, stream>>>(h2, wwT + (size_t)3 * CC * CC, wb, cAt, cBt,
                                               w1Tg, fc1b, fc2w, fc2b, (float*)d_out);
    }
}

// Round 16
// 693.799 us; speedup vs baseline: 1.5687x; 1.5687x over previous
//
#include <hip/hip_runtime.h>
#include <math.h>

#define BB 32
#define SS 65536
#define CC 20
#define NM 16
#define HH 128
#define RP 264   // DFT LDS row pitch (bf16 elems)
#define WP 72    // hT row pitch (bf16 elems): 36 dwords; b128-aligned rows
#define NSLOT 16

using short8  = __attribute__((ext_vector_type(8))) short;
using floatx4 = __attribute__((ext_vector_type(4))) float;

__device__ __forceinline__ unsigned short f2bf(float f) {
    union { float f; unsigned u; } v; v.f = f;
    unsigned u = v.u;
    return (unsigned short)((u + 0x7FFFu + ((u >> 16) & 1u)) >> 16);   // RNE
}
__device__ __forceinline__ float bf2f(unsigned short h) {
    union { unsigned u; float f; } v; v.u = ((unsigned)h) << 16; return v.f;
}
__device__ __forceinline__ unsigned short f2bflo(float a) {
    return f2bf(a - bf2f(f2bf(a)));
}

// Tanh-form gelu, native exp2/rcp (R11). |delta| vs erf-gelu ~3e-4.
// NOTE (R15 lesson): keep all WEIGHT reads as scalar float loads — vector-
// typed (float2/float4) loads from uniform addresses defeat s_load
// scalarization and regress 2.3x.
__device__ __forceinline__ float gelu_fast(float v) {
    float u = v * v;
    float inner = v * fmaf(0.0356774081f, u, 0.7978845608f);
    float e = __builtin_amdgcn_exp2f(inner * 2.8853900818f);
    float r = __builtin_amdgcn_rcpf(e + 1.0f);
    return fmaf(-v, r, v);
}

// ---------------- k_prep: max-reduce + zero cP + build w1T(global) ----------
__global__ __launch_bounds__(256) void k_prep(const float* __restrict__ pd,
                                              const float* __restrict__ w1,
                                              float* __restrict__ invmax,
                                              float* __restrict__ cP,
                                              unsigned short* __restrict__ w1Tg) {
    int bx = blockIdx.x;
    if (bx == 0) {
        __shared__ float red[256];
        int t = threadIdx.x;
        float m = -1e30f;
        for (int i = t; i < SS; i += 256) m = fmaxf(m, pd[i]);
        red[t] = m; __syncthreads();
        for (int off = 128; off > 0; off >>= 1) {
            if (t < off) red[t] = fmaxf(red[t], red[t + off]);
            __syncthreads();
        }
        if (t == 0) invmax[0] = 1.0f / red[0];
    } else if (bx <= 1280) {
        int idx = (bx - 1) * 256 + threadIdx.x;   // 1280*256 float4 = 4*16*32*640 floats
        float4 z = {0.f, 0.f, 0.f, 0.f};
        ((float4*)cP)[idx] = z;
    } else {
        for (int idx = threadIdx.x; idx < HH * 64; idx += 256) {
            int j = idx >> 6, k = idx & 63;
            unsigned short r = 0;
            if (k < CC) r = f2bf(w1[k * HH + j]);
            else if (k >= 32 && k < 32 + CC) r = f2bflo(w1[(k - 32) * HH + j]);
            w1Tg[idx] = r;
        }
    }
}

// ---------------- shared DFT tail: LDS-staged MFMA partial DFT --------------
__device__ __forceinline__ void dft_phase(unsigned short* sh_hA, unsigned short* sh_ph,
                                          int tid, float* cPdst) {
    int wave = tid >> 6, lane = tid & 63;
    int quad = lane >> 4, frow = lane & 15;
    floatx4 acc00 = {0.f,0.f,0.f,0.f}, acc01 = {0.f,0.f,0.f,0.f};
    floatx4 acc10 = {0.f,0.f,0.f,0.f}, acc11 = {0.f,0.f,0.f,0.f};
    int kb = wave * 64 + quad * 8;
    #pragma unroll
    for (int kc = 0; kc < 2; ++kc) {
        int k = kb + kc * 32;
        short8 a0 = *(const short8*)(sh_hA + frow * RP + k);
        short8 a1 = *(const short8*)(sh_hA + (16 + frow) * RP + k);
        short8 bc = *(const short8*)(sh_ph + frow * RP + k);
        short8 bs = *(const short8*)(sh_ph + (16 + frow) * RP + k);
        acc00 = __builtin_amdgcn_mfma_f32_16x16x32_bf16(a0, bc, acc00, 0, 0, 0);
        acc01 = __builtin_amdgcn_mfma_f32_16x16x32_bf16(a0, bs, acc01, 0, 0, 0);
        acc10 = __builtin_amdgcn_mfma_f32_16x16x32_bf16(a1, bc, acc10, 0, 0, 0);
        acc11 = __builtin_amdgcn_mfma_f32_16x16x32_bf16(a1, bs, acc11, 0, 0, 0);
    }
    __syncthreads();
    float* red = (float*)sh_hA;
    #pragma unroll
    for (int r = 0; r < 4; ++r) {
        red[wave * 1024 + 0 * 256 + r * 64 + lane] = acc00[r];
        red[wave * 1024 + 1 * 256 + r * 64 + lane] = acc01[r];
        red[wave * 1024 + 2 * 256 + r * 64 + lane] = acc10[r];
        red[wave * 1024 + 3 * 256 + r * 64 + lane] = acc11[r];
    }
    __syncthreads();
    #pragma unroll
    for (int ii = 0; ii < 4; ++ii) {
        int idx = ii * 256 + tid;
        float v = red[idx] + red[1024 + idx] + red[2048 + idx] + red[3072 + idx];
        int f = idx >> 8;
        int r = (idx >> 6) & 3, ln = idx & 63;
        int o = (f >> 1) * 16 + (ln >> 4) * 4 + r;   // D row = quad*4+reg
        int m = ln & 15;                              // D col = lane&15
        if (o < CC) atomicAdd(cPdst + (f & 1) * 320 + o * 16 + m, v);
    }
}

// ---------------- k_fc0_dft: h2 (paired bf16 dwords) = fc0; DFT partials ----
// h2[p*SS+s]: lo16 = channel 2p, hi16 = channel 2p+1 — full-dword accesses
// (R13's strided ushort loads compiled to d16 pairs -> false-dep stalls).
__global__ __launch_bounds__(256, 4) void k_fc0_dft(const float* __restrict__ x,
        const float* __restrict__ pd, const float* __restrict__ w,
        const float* __restrict__ bias, const float* __restrict__ invmax,
        unsigned* __restrict__ h2, float* __restrict__ cP0) {
    __shared__ __align__(16) unsigned short sh_hA[32 * RP];
    __shared__ __align__(16) unsigned short sh_ph[32 * RP];
    int tid = threadIdx.x;
    {
        unsigned* z = (unsigned*)(sh_hA + CC * RP);
        for (int i = tid; i < (32 - CC) * RP / 2; i += 256) z[i] = 0;
    }
    int b = blockIdx.y;
    int s = blockIdx.x * 256 + tid;
    float xv = x[(size_t)b * SS + s];
    float g  = pd[s] * invmax[0];
    unsigned* hp2 = h2 + (size_t)b * (CC / 2) * SS + s;
    float u = (float)s * (1.0f / 32768.0f);
    float s1, c1; sincospif(u, &s1, &c1);
    float cm = 1.0f, sm = 0.0f;
    #pragma unroll
    for (int m = 0; m < NM; ++m) {
        sh_ph[m * RP + tid]        = f2bf(cm);
        sh_ph[(16 + m) * RP + tid] = f2bf(sm);
        float cn = cm * c1 - sm * s1;
        sm = sm * c1 + cm * s1;
        cm = cn;
    }
    #pragma unroll
    for (int p = 0; p < CC / 2; ++p) {
        int c0 = 2 * p, c1i = 2 * p + 1;
        float v0 = xv * w[c0]  + g * w[CC + c0]  + bias[c0];
        float v1 = xv * w[c1i] + g * w[CC + c1i] + bias[c1i];
        unsigned short a0 = f2bf(v0), a1 = f2bf(v1);
        hp2[(size_t)p * SS] = (unsigned)a0 | ((unsigned)a1 << 16);
        sh_hA[c0 * RP + tid]  = a0;
        sh_hA[c1i * RP + tid] = a1;
    }
    __syncthreads();
    dft_phase(sh_hA, sh_ph, tid, cP0 + ((size_t)(blockIdx.x & (NSLOT - 1)) * BB + b) * 640);
}

// ---------------- k_point_dft (layers 0..2: gelu + next-layer DFT) ----------
__global__ __launch_bounds__(256, 4) void k_point_dft(unsigned* __restrict__ h2,
        const float* __restrict__ ww, const float* __restrict__ wb,
        const float* __restrict__ cA, const float* __restrict__ cB,
        float* __restrict__ cPn) {
    __shared__ __align__(16) unsigned short sh_hA[32 * RP];
    __shared__ __align__(16) unsigned short sh_ph[32 * RP];
    int tid = threadIdx.x;
    int b = blockIdx.y;
    {
        unsigned* z = (unsigned*)(sh_hA + CC * RP);
        for (int i = tid; i < (32 - CC) * RP / 2; i += 256) z[i] = 0;
    }
    const float* wA = cA + (size_t)b * CC * NM;
    const float* wB = cB + (size_t)b * CC * NM;
    int s = blockIdx.x * 256 + tid;
    unsigned* hp2 = h2 + (size_t)b * (CC / 2) * SS + s;
    float u = (float)s * (1.0f / 32768.0f);
    float s1, c1; sincospif(u, &s1, &c1);
    float cm[NM], sm[NM];
    cm[0] = 1.0f; sm[0] = 0.0f;
    #pragma unroll
    for (int m = 1; m < NM; ++m) {
        cm[m] = cm[m - 1] * c1 - sm[m - 1] * s1;
        sm[m] = sm[m - 1] * c1 + cm[m - 1] * s1;
    }
    #pragma unroll
    for (int m = 0; m < NM; ++m) {
        sh_ph[m * RP + tid]        = f2bf(cm[m]);
        sh_ph[(16 + m) * RP + tid] = f2bf(sm[m]);
    }
    float hv[CC];
    #pragma unroll
    for (int p = 0; p < CC / 2; ++p) {
        unsigned hw = hp2[(size_t)p * SS];
        hv[2 * p]     = bf2f((unsigned short)(hw & 0xFFFFu));
        hv[2 * p + 1] = bf2f((unsigned short)(hw >> 16));
    }
    #pragma unroll 2
    for (int p = 0; p < CC / 2; ++p) {
        int o0 = 2 * p, o1 = 2 * p + 1;
        float a0 = wb[o0], a1 = wb[o1];
        #pragma unroll
        for (int c = 0; c < CC; ++c) {
            a0 += ww[o0 * CC + c] * hv[c];
            a1 += ww[o1 * CC + c] * hv[c];
        }
        #pragma unroll
        for (int m = 0; m < NM; ++m) {
            a0 += wA[o0 * NM + m] * cm[m] + wB[o0 * NM + m] * sm[m];
            a1 += wA[o1 * NM + m] * cm[m] + wB[o1 * NM + m] * sm[m];
        }
        a0 = gelu_fast(a0);
        a1 = gelu_fast(a1);
        unsigned short b0 = f2bf(a0), b1 = f2bf(a1);
        hp2[(size_t)p * SS] = (unsigned)b0 | ((unsigned)b1 << 16);
        sh_hA[o0 * RP + tid] = b0;
        sh_hA[o1 * RP + tid] = b1;
    }
    __syncthreads();
    dft_phase(sh_hA, sh_ph, tid, cPn + ((size_t)(blockIdx.x & (NSLOT - 1)) * BB + b) * 640);
}

// ---------------- k_mix: 16-slot partial reduce + complex mixing ------------
__global__ __launch_bounds__(320) void k_mix(const float* __restrict__ cP,
                                             const float* __restrict__ wre, const float* __restrict__ wim,
                                             float* __restrict__ cA, float* __restrict__ cB) {
    int b = blockIdx.x, tid = threadIdx.x;
    __shared__ float PQ[640];
    const float* base = cP + (size_t)b * 640;
    int i = tid >> 4, m = tid & 15;
    float sP = 0.f, sQ = 0.f;
    #pragma unroll 4
    for (int sl = 0; sl < NSLOT; ++sl) {
        sP += base[(size_t)sl * BB * 640 + tid];
        sQ += base[(size_t)sl * BB * 640 + 320 + tid];
    }
    PQ[i * 32 + m]      = sP;
    PQ[i * 32 + 16 + m] = sQ;
    __syncthreads();
    int o = i;
    float reY = 0.f, imY = 0.f;
    #pragma unroll
    for (int c = 0; c < CC; ++c) {
        float P = PQ[c * 32 + m], Q = PQ[c * 32 + 16 + m];
        float wr = wre[(size_t)(c * CC + o) * NM + m];
        float wi = wim[(size_t)(c * CC + o) * NM + m];
        reY += P * wr + Q * wi;                // X = P - iQ
        imY += P * wi - Q * wr;
    }
    const float invS = 1.0f / (float)SS;
    float a, bb;
    if (m == 0) { a = reY * invS; bb = 0.0f; } // irfft drops Im(DC)
    else        { a = 2.0f * reY * invS; bb = -2.0f * imY * invS; }
    cA[(size_t)(b * CC + o) * NM + m] = a;
    cB[(size_t)(b * CC + o) * NM + m] = bb;
}

// ---------------- k_point_final: layer-3 point op + fc1 MFMA + gelu + fc2 ---
// (256,4): VGPR cap 128 >> natural 76 (no squeeze risk); LDS 37.9 KB admits
// 4 blocks/CU — R14 ran at 34% occupancy with 55% VALUBusy (latency-stalled).
__global__ __launch_bounds__(256, 4) void k_point_final(const unsigned* __restrict__ h2,
        const float* __restrict__ ww, const float* __restrict__ wb,
        const float* __restrict__ cA, const float* __restrict__ cB,
        const unsigned short* __restrict__ w1Tg, const float* __restrict__ b1,
        const float* __restrict__ w2, const float* __restrict__ b2,
        float* __restrict__ out) {
    __shared__ __align__(16) unsigned short hT[256 * WP];   // 36.9 KB
    __shared__ float outS[256];
    int tid = threadIdx.x;
    int b = blockIdx.y;
    const float* wA = cA + (size_t)b * CC * NM;
    const float* wB = cB + (size_t)b * CC * NM;

    // point op (layer 3, no gelu), pack own hT row
    int s = blockIdx.x * 256 + tid;
    const unsigned* hp2 = h2 + (size_t)b * (CC / 2) * SS + s;
    float u = (float)s * (1.0f / 32768.0f);
    float s1, c1; sincospif(u, &s1, &c1);
    float cm[NM], sm[NM];
    cm[0] = 1.0f; sm[0] = 0.0f;
    #pragma unroll
    for (int m = 1; m < NM; ++m) {
        cm[m] = cm[m - 1] * c1 - sm[m - 1] * s1;
        sm[m] = sm[m - 1] * c1 + cm[m - 1] * s1;
    }
    float hv[CC];
    #pragma unroll
    for (int p = 0; p < CC / 2; ++p) {
        unsigned hw = hp2[(size_t)p * SS];
        hv[2 * p]     = bf2f((unsigned short)(hw & 0xFFFFu));
        hv[2 * p + 1] = bf2f((unsigned short)(hw >> 16));
    }
    short8 rowf[8];
    #pragma unroll
    for (int ch = 0; ch < 8; ++ch) rowf[ch] = (short8){0,0,0,0,0,0,0,0};
    #pragma unroll        // FULL unroll required (R5 scratch lesson)
    for (int o = 0; o < CC; ++o) {
        float a = wb[o];
        #pragma unroll
        for (int c = 0; c < CC; ++c) a += ww[o * CC + c] * hv[c];
        #pragma unroll
        for (int m = 0; m < NM; ++m)
            a += wA[o * NM + m] * cm[m] + wB[o * NM + m] * sm[m];
        unsigned short hi = f2bf(a);
        rowf[o >> 3][o & 7]       = (short)hi;
        rowf[4 + (o >> 3)][o & 7] = (short)f2bf(a - bf2f(hi));
    }
    #pragma unroll
    for (int ch = 0; ch < 8; ++ch)
        *(short8*)(hT + tid * WP + ch * 8) = rowf[ch];
    __syncthreads();

    // fc1 B-fragments from global (L2-resident) — after the point-op (R8)
    int wave = tid >> 6, lane = tid & 63;
    int col = lane & 15, quad = lane >> 4;
    short8 bhi[8], blo[8];
    #pragma unroll
    for (int nt = 0; nt < 8; ++nt) {
        bhi[nt] = *(const short8*)(w1Tg + (size_t)(nt * 16 + col) * 64 + quad * 8);
        blo[nt] = *(const short8*)(w1Tg + (size_t)(nt * 16 + col) * 64 + 32 + quad * 8);
    }
    float lb1r[8], w2r[8];
    #pragma unroll
    for (int nt = 0; nt < 8; ++nt) { lb1r[nt] = b1[nt * 16 + col]; w2r[nt] = w2[nt * 16 + col]; }
    float b2v = b2[0];
    #pragma unroll
    for (int mt = 0; mt < 4; ++mt) {
        int srow = wave * 64 + mt * 16 + col;     // A row m = lane&15
        short8 ahi = *(const short8*)(hT + srow * WP + quad * 8);
        short8 alo = *(const short8*)(hT + srow * WP + 32 + quad * 8);
        float part[4] = {0.f, 0.f, 0.f, 0.f};
        #pragma unroll
        for (int nt = 0; nt < 8; ++nt) {
            floatx4 a = {0.f, 0.f, 0.f, 0.f};
            a = __builtin_amdgcn_mfma_f32_16x16x32_bf16(ahi, bhi[nt], a, 0, 0, 0);
            a = __builtin_amdgcn_mfma_f32_16x16x32_bf16(ahi, blo[nt], a, 0, 0, 0);
            a = __builtin_amdgcn_mfma_f32_16x16x32_bf16(alo, bhi[nt], a, 0, 0, 0);
            #pragma unroll
            for (int r = 0; r < 4; ++r) {
                float t = gelu_fast(a[r] + lb1r[nt]);
                part[r] += t * w2r[nt];
            }
        }
        #pragma unroll
        for (int r = 0; r < 4; ++r) {
            float p = part[r];
            p += __shfl_xor(p, 1, 64);
            p += __shfl_xor(p, 2, 64);
            p += __shfl_xor(p, 4, 64);
            p += __shfl_xor(p, 8, 64);
            if (col == 0) outS[wave * 64 + mt * 16 + quad * 4 + r] = p + b2v;
        }
    }
    __syncthreads();
    out[(size_t)b * SS + blockIdx.x * 256 + tid] = outS[tid];
}

extern "C" void kernel_launch(void* const* d_in, const int* in_sizes, int n_in,
                              void* d_out, int out_size, void* d_ws, size_t ws_size,
                              hipStream_t stream) {
    (void)in_sizes; (void)n_in; (void)out_size; (void)ws_size;
    const float* x    = (const float*)d_in[0];
    const float* pd   = (const float*)d_in[1];
    const float* fc0w = (const float*)d_in[2];
    const float* fc0b = (const float*)d_in[3];
    const float* fc1w = (const float*)d_in[4];
    const float* fc1b = (const float*)d_in[5];
    const float* fc2w = (const float*)d_in[6];
    const float* fc2b = (const float*)d_in[7];

    char* ws = (char*)d_ws;
    unsigned* h2 = (unsigned*)ws;
    size_t off = (size_t)BB * (CC / 2) * SS * 4;                      // 83.9 MB (paired bf16)
    float* cP = (float*)(ws + off); off += (size_t)4 * NSLOT * BB * 640 * 4;  // 5.24 MB
    float* cA = (float*)(ws + off); off += (size_t)BB * CC * NM * 4;
    float* cB = (float*)(ws + off); off += (size_t)BB * CC * NM * 4;
    float* invmax = (float*)(ws + off); off += 256;
    unsigned short* w1Tg = (unsigned short*)(ws + off); off += (size_t)HH * 64 * 2;  // 16 KB
    const size_t CPL = (size_t)NSLOT * BB * 640;   // floats per layer-slot set

    dim3 gBS(SS / 256, BB);

    k_prep<<<1282, 256, 0, stream>>>(pd, fc1w, invmax, cP, w1Tg);
    k_fc0_dft<<<gBS, 256, 0, stream>>>(x, pd, fc0w, fc0b, invmax, h2, cP);

    for (int l = 0; l < 3; ++l) {
        const float* wre = (const float*)d_in[8 + 4 * l];
        const float* wim = (const float*)d_in[9 + 4 * l];
        const float* ww  = (const float*)d_in[10 + 4 * l];
        const float* wb  = (const float*)d_in[11 + 4 * l];
        k_mix<<<BB, 320, 0, stream>>>(cP + (size_t)l * CPL, wre, wim, cA, cB);
        k_point_dft<<<gBS, 256, 0, stream>>>(h2, ww, wb, cA, cB,
                                             cP + (size_t)(l + 1) * CPL);
    }
    {   // layer 3 fused with fc1/gelu/fc2
        const float* wre = (const float*)d_in[20];
        const float* wim = (const float*)d_in[21];
        const float* ww  = (const float*)d_in[22];
        const float* wb  = (const float*)d_in[23];
        k_mix<<<BB, 320, 0, stream>>>(cP + (size_t)3 * CPL, wre, wim, cA, cB);
        k_point_final<<<gBS, 256, 0, stream>>>(h2, ww, wb, cA, cB,
                                               w1Tg, fc1b, fc2w, fc2b, (float*)d_out);
    }
}